// Round 1
// baseline (373.627 us; speedup 1.0000x reference)
//
#include <hip/hip_runtime.h>

// out[b,c,h,w] = x[b,c,h+1,w] - x[b,c,h,w]
// x: (16, 64, 512, 512) fp32, out: (16, 64, 511, 512) fp32
// Vectorized float4: W = 512 floats = 128 float4 per row.

#define H_IN 512
#define H_OUT 511
#define W4 128              // 512 floats / 4
#define PLANE_OUT (H_OUT * W4)   // float4s per (b,c) plane in out = 65408
#define PLANE_IN  (H_IN * W4)    // float4s per (b,c) plane in x = 65536

__global__ __launch_bounds__(256) void PartialDerivative_kernel(
    const float4* __restrict__ x, float4* __restrict__ out) {
    const int tid = blockIdx.x * blockDim.x + threadIdx.x;  // over PLANE_OUT
    if (tid >= PLANE_OUT) return;
    const int bc = blockIdx.y;   // 0..1023

    const size_t in_base = (size_t)bc * PLANE_IN + (size_t)tid;  // tid = h*128 + w4
    float4 a = x[in_base];        // row h
    float4 b = x[in_base + W4];   // row h+1
    float4 r;
    r.x = b.x - a.x;
    r.y = b.y - a.y;
    r.z = b.z - a.z;
    r.w = b.w - a.w;
    out[(size_t)bc * PLANE_OUT + (size_t)tid] = r;
}

extern "C" void kernel_launch(void* const* d_in, const int* in_sizes, int n_in,
                              void* d_out, int out_size, void* d_ws, size_t ws_size,
                              hipStream_t stream) {
    const float4* x = (const float4*)d_in[0];
    float4* out = (float4*)d_out;

    dim3 block(256);
    dim3 grid((PLANE_OUT + 255) / 256, 16 * 64);  // (256, 1024)
    PartialDerivative_kernel<<<grid, block, 0, stream>>>(x, out);
}